// Round 1
// baseline (1339.859 us; speedup 1.0000x reference)
//
#include <hip/hip_runtime.h>

#define NN 1000000
#define NE 32000000
#define SCAN_B 256

// bucket decomposition: dst-bucket = d >> 12 (4096 nodes), sub-bucket = src quartile
// logical bucket = (d >> 12) * 4 | (s >> 18)  -> gather working set 2MB per phase,
// which is L2-resident per XCD (4 MiB), vs the 8MB xd table that thrashed L2.
#define BK_SH 12
#define BK_SZ 4096
#define NB 245                       // ceil(NN / BK_SZ)
#define SUB 4                        // src-range sub-buckets per dst bucket
#define SUB_SH 18                    // s >> 18 in [0,3] since s < 2^20
#define LB (NB * SUB)                // 980 logical buckets
#define GAB 256                      // edge-chunk blocks for passes A and C
#define CHUNK 125000                 // 256 * 125000 = 32,000,000 exactly (div by 4)
#define NL (LB * GAB)                // hist length = 250880 (divisible by 256)
#define NBS (NL / SCAN_B)            // 980 scan blocks (exact)

typedef int vi4 __attribute__((ext_vector_type(4)));

// ---- dtype detector: flag=1 if edge_index is int64, 0 if int32 ----
// int64 little-endian values < 2^31 have all-zero high (odd) words.
__global__ void detect_kernel(const int* __restrict__ ei, int* __restrict__ flag) {
    __shared__ int nz;
    if (threadIdx.x == 0) nz = 0;
    __syncthreads();
    int w = ei[2 * threadIdx.x + 1];
    if (w != 0) atomicAdd(&nz, 1);
    __syncthreads();
    if (threadIdx.x == 0) *flag = (nz == 0) ? 1 : 0;
}

// ---- pass A: per-block LDS histogram over logical buckets -> hist[lb*GAB + g] ----
__global__ void passA_kernel(const int* __restrict__ ei, int* __restrict__ hist,
                             const int* __restrict__ flagp, int nE) {
    __shared__ int h[LB];
    int t = threadIdx.x;
    for (int b = t; b < LB; b += 1024) h[b] = 0;
    __syncthreads();
    int shift = *flagp;
    int start = blockIdx.x * CHUNK;
    int end = min(start + CHUNK, nE);
    if (shift == 0) {
        const int* srcp = ei;
        const int* dstp = ei + nE;
        for (int i = start + (t << 2); i < end; i += 4096) {
            vi4 s = __builtin_nontemporal_load((const vi4*)(srcp + i));
            vi4 d = __builtin_nontemporal_load((const vi4*)(dstp + i));
            atomicAdd(&h[((d.x >> BK_SH) << 2) | (s.x >> SUB_SH)], 1);
            atomicAdd(&h[((d.y >> BK_SH) << 2) | (s.y >> SUB_SH)], 1);
            atomicAdd(&h[((d.z >> BK_SH) << 2) | (s.z >> SUB_SH)], 1);
            atomicAdd(&h[((d.w >> BK_SH) << 2) | (s.w >> SUB_SH)], 1);
        }
    } else {
        for (int i = start + t; i < end; i += 1024) {
            int s = __builtin_nontemporal_load(ei + ((size_t)i << 1));
            int d = __builtin_nontemporal_load(ei + (((size_t)(nE + i)) << 1));
            atomicAdd(&h[((d >> BK_SH) << 2) | (s >> SUB_SH)], 1);
        }
    }
    __syncthreads();
    for (int b = t; b < LB; b += 1024)
        hist[(size_t)b * GAB + blockIdx.x] = h[b];
}

// ---- scan stage 1: per-block exclusive scan (in-place), block sums ----
__global__ void scan1_kernel(int* __restrict__ data, int* __restrict__ bsum, int n) {
    __shared__ int sm[SCAN_B];
    int t = threadIdx.x;
    int i = blockIdx.x * SCAN_B + t;
    int v = (i < n) ? data[i] : 0;
    sm[t] = v;
    __syncthreads();
    for (int o = 1; o < SCAN_B; o <<= 1) {
        int a = (t >= o) ? sm[t - o] : 0;
        __syncthreads();
        sm[t] += a;
        __syncthreads();
    }
    if (i < n) data[i] = sm[t] - v;
    if (t == SCAN_B - 1) bsum[blockIdx.x] = sm[t];
}

// ---- scan stage 2: exclusive scan of block sums (1 block, up to 4096) ----
__global__ void scan2_kernel(int* __restrict__ bsum, int nb) {
    __shared__ int sm[1024];
    int t = threadIdx.x;
    int base = t * 4;
    int v[4];
    int s = 0;
#pragma unroll
    for (int j = 0; j < 4; ++j) {
        v[j] = (base + j < nb) ? bsum[base + j] : 0;
        s += v[j];
    }
    sm[t] = s;
    __syncthreads();
    for (int o = 1; o < 1024; o <<= 1) {
        int a = (t >= o) ? sm[t - o] : 0;
        __syncthreads();
        sm[t] += a;
        __syncthreads();
    }
    int run = sm[t] - s;
#pragma unroll
    for (int j = 0; j < 4; ++j) {
        if (base + j < nb) bsum[base + j] = run;
        run += v[j];
    }
}

// ---- pass C: scatter packed edges into logical-bucket-contiguous regions ----
// pairs[idx] = s | (d_local << 20)   (s < 2^20, d_local < 2^12)
__global__ void passC_kernel(const int* __restrict__ ei, const int* __restrict__ hist,
                             const int* __restrict__ bsum, unsigned int* __restrict__ pairs,
                             const int* __restrict__ flagp, int nE) {
    __shared__ int cur[LB];
    int t = threadIdx.x;
    for (int b = t; b < LB; b += 1024) {
        int flat = b * GAB + blockIdx.x;
        cur[b] = hist[flat] + bsum[flat >> 8];
    }
    __syncthreads();
    int shift = *flagp;
    int start = blockIdx.x * CHUNK;
    int end = min(start + CHUNK, nE);
    if (shift == 0) {
        const int* srcp = ei;
        const int* dstp = ei + nE;
        for (int i = start + (t << 2); i < end; i += 4096) {
            vi4 s = __builtin_nontemporal_load((const vi4*)(srcp + i));
            vi4 d = __builtin_nontemporal_load((const vi4*)(dstp + i));
            int idx;
            idx = atomicAdd(&cur[((d.x >> BK_SH) << 2) | (s.x >> SUB_SH)], 1);
            pairs[idx] = (unsigned)s.x | ((unsigned)(d.x & (BK_SZ - 1)) << 20);
            idx = atomicAdd(&cur[((d.y >> BK_SH) << 2) | (s.y >> SUB_SH)], 1);
            pairs[idx] = (unsigned)s.y | ((unsigned)(d.y & (BK_SZ - 1)) << 20);
            idx = atomicAdd(&cur[((d.z >> BK_SH) << 2) | (s.z >> SUB_SH)], 1);
            pairs[idx] = (unsigned)s.z | ((unsigned)(d.z & (BK_SZ - 1)) << 20);
            idx = atomicAdd(&cur[((d.w >> BK_SH) << 2) | (s.w >> SUB_SH)], 1);
            pairs[idx] = (unsigned)s.w | ((unsigned)(d.w & (BK_SZ - 1)) << 20);
        }
    } else {
        for (int i = start + t; i < end; i += 1024) {
            int s = __builtin_nontemporal_load(ei + ((size_t)i << 1));
            int d = __builtin_nontemporal_load(ei + (((size_t)(nE + i)) << 1));
            int idx = atomicAdd(&cur[((d >> BK_SH) << 2) | (s >> SUB_SH)], 1);
            pairs[idx] = (unsigned)s | ((unsigned)(d & (BK_SZ - 1)) << 20);
        }
    }
}

__device__ __forceinline__ void bucket_range(const int* __restrict__ hist,
                                             const int* __restrict__ bsum,
                                             int b, int nE, int& base, int& endp) {
    int f0 = (b * SUB) * GAB;
    base = hist[f0] + bsum[f0 >> 8];
    if (b + 1 < NB) {
        int f1 = ((b + 1) * SUB) * GAB;
        endp = hist[f1] + bsum[f1 >> 8];
    } else {
        endp = nE;
    }
}

// ---- pass D0: per-bucket degree count -> dinv, xd = x * dinv ----
__global__ void passD0_kernel(const unsigned int* __restrict__ pairs,
                              const int* __restrict__ hist, const int* __restrict__ bsum,
                              const float2* __restrict__ x,
                              float* __restrict__ dinv, float2* __restrict__ xd,
                              int nE, int nN) {
    __shared__ int degl[BK_SZ];
    int t = threadIdx.x;
    int b = blockIdx.x;
    for (int j = t; j < BK_SZ; j += 1024) degl[j] = 0;
    __syncthreads();
    int base, endp;
    bucket_range(hist, bsum, b, nE, base, endp);
    for (int k = base + (t << 2); k < endp; k += 4096) {
#pragma unroll
        for (int j = 0; j < 4; ++j)
            if (k + j < endp) {
                unsigned int p = __builtin_nontemporal_load(pairs + k + j);
                atomicAdd(&degl[p >> 20], 1);
            }
    }
    __syncthreads();
    for (int j = t; j < BK_SZ; j += 1024) {
        int nid = (b << BK_SH) + j;
        if (nid < nN) {
            float di = rsqrtf((float)(degl[j] + 1));   // +1 self-loop
            dinv[nid] = di;
            float2 v = x[nid];
            xd[nid] = make_float2(v.x * di, v.y * di);
        }
    }
}

// ---- pass L1: per-bucket aggregate xd, fuse W1/b1/relu/W2 -> hd = h2*dinv ----
__global__ void passL1_kernel(const unsigned int* __restrict__ pairs,
                              const int* __restrict__ hist, const int* __restrict__ bsum,
                              const float* __restrict__ dinv, const float2* __restrict__ xd,
                              const float* __restrict__ W1, const float* __restrict__ b1,
                              const float* __restrict__ W2,
                              float* __restrict__ hd, int nE, int nN) {
    __shared__ float ax[BK_SZ];
    __shared__ float ay[BK_SZ];
    int t = threadIdx.x;
    int b = blockIdx.x;
    for (int j = t; j < BK_SZ; j += 1024) { ax[j] = 0.f; ay[j] = 0.f; }
    __syncthreads();
    int base, endp;
    bucket_range(hist, bsum, b, nE, base, endp);
    for (int k = base + (t << 2); k < endp; k += 4096) {
        unsigned int p[4];
        float2 v[4];
        int lim = min(4, endp - k);
#pragma unroll
        for (int j = 0; j < 4; ++j)
            if (j < lim) p[j] = __builtin_nontemporal_load(pairs + k + j);
#pragma unroll
        for (int j = 0; j < 4; ++j)
            if (j < lim) v[j] = xd[p[j] & 0xFFFFF];
#pragma unroll
        for (int j = 0; j < 4; ++j)
            if (j < lim) {
                int dl = p[j] >> 20;
                atomicAdd(&ax[dl], v[j].x);
                atomicAdd(&ay[dl], v[j].y);
            }
    }
    __syncthreads();
    for (int j = t; j < BK_SZ; j += 1024) {
        int nid = (b << BK_SH) + j;
        if (nid < nN) {
            float dd = dinv[nid];
            float2 xs = xd[nid];
            float AX = (ax[j] + xs.x * dd) * dd;       // self-loop: xd*dd
            float AY = (ay[j] + xs.y * dd) * dd;
            float acc = 0.f;
#pragma unroll
            for (int c = 0; c < 8; ++c) {
                float h = fmaf(AX, W1[c], fmaf(AY, W1[8 + c], b1[c]));
                acc = fmaf(fmaxf(h, 0.f), W2[c], acc);
            }
            hd[nid] = acc * dd;                        // hd = h2 * dinv
        }
    }
}

// ---- pass L2: per-bucket aggregate hd, fuse sigmoid -> out ----
__global__ void passL2_kernel(const unsigned int* __restrict__ pairs,
                              const int* __restrict__ hist, const int* __restrict__ bsum,
                              const float* __restrict__ dinv, const float* __restrict__ hd,
                              const float* __restrict__ b2,
                              float* __restrict__ out, int nE, int nN) {
    __shared__ float ag[BK_SZ];
    int t = threadIdx.x;
    int b = blockIdx.x;
    for (int j = t; j < BK_SZ; j += 1024) ag[j] = 0.f;
    __syncthreads();
    int base, endp;
    bucket_range(hist, bsum, b, nE, base, endp);
    for (int k = base + (t << 2); k < endp; k += 4096) {
        unsigned int p[4];
        float v[4];
        int lim = min(4, endp - k);
#pragma unroll
        for (int j = 0; j < 4; ++j)
            if (j < lim) p[j] = __builtin_nontemporal_load(pairs + k + j);
#pragma unroll
        for (int j = 0; j < 4; ++j)
            if (j < lim) v[j] = hd[p[j] & 0xFFFFF];
#pragma unroll
        for (int j = 0; j < 4; ++j)
            if (j < lim) atomicAdd(&ag[p[j] >> 20], v[j]);
    }
    __syncthreads();
    for (int j = t; j < BK_SZ; j += 1024) {
        int nid = (b << BK_SH) + j;
        if (nid < nN) {
            float z = fmaf(dinv[nid], ag[j] + hd[nid], b2[0]);
            out[nid] = 1.f / (1.f + expf(-z));
        }
    }
}

// ================= fallback (small-workspace) atomic path =================

__global__ void deg_kernel(const int* __restrict__ ei, int* __restrict__ deg,
                           const int* __restrict__ flagp, int nE) {
    int i = blockIdx.x * blockDim.x + threadIdx.x;
    if (i >= nE) return;
    int shift = *flagp;
    int d = ei[((size_t)nE << shift) + ((size_t)i << shift)];
    atomicAdd(&deg[d], 1);
}

__global__ void prep_kernel(const int* __restrict__ deg, const float2* __restrict__ x,
                            float* __restrict__ dinv, float2* __restrict__ xd, int nN) {
    int i = blockIdx.x * blockDim.x + threadIdx.x;
    if (i >= nN) return;
    float di = rsqrtf((float)(deg[i] + 1));
    dinv[i] = di;
    float2 v = x[i];
    xd[i] = make_float2(v.x * di, v.y * di);
}

__device__ __forceinline__ void load_edge(const int* __restrict__ ei, int shift,
                                          int nE, int i, int& s, int& d) {
    s = ei[(size_t)i << shift];
    d = ei[((size_t)nE << shift) + ((size_t)i << shift)];
}

__global__ void l1a_kernel(const int* __restrict__ ei, const float2* __restrict__ xd,
                           float* __restrict__ agg, const int* __restrict__ flagp, int nE) {
    int i = blockIdx.x * blockDim.x + threadIdx.x;
    if (i >= nE) return;
    int shift = *flagp;
    int s, d;
    load_edge(ei, shift, nE, i, s, d);
    float2 v = xd[s];
    unsafeAtomicAdd(&agg[(size_t)d * 2], v.x);
    unsafeAtomicAdd(&agg[(size_t)d * 2 + 1], v.y);
}

__global__ void h2f_kernel(const float2* __restrict__ agg, const float2* __restrict__ xd,
                           const float* __restrict__ dinv, const float* __restrict__ W1,
                           const float* __restrict__ b1, const float* __restrict__ W2,
                           float* __restrict__ hd, int nN) {
    int d = blockIdx.x * blockDim.x + threadIdx.x;
    if (d >= nN) return;
    float dd = dinv[d];
    float2 a = agg[d];
    float2 xs = xd[d];
    float ax = (a.x + xs.x * dd) * dd;
    float ay = (a.y + xs.y * dd) * dd;
    float acc = 0.f;
#pragma unroll
    for (int j = 0; j < 8; ++j) {
        float h = fmaf(ax, W1[j], fmaf(ay, W1[8 + j], b1[j]));
        acc = fmaf(fmaxf(h, 0.f), W2[j], acc);
    }
    hd[d] = acc * dd;
}

__global__ void l2a_kernel(const int* __restrict__ ei, const float* __restrict__ hd,
                           float* __restrict__ out2, const int* __restrict__ flagp, int nE) {
    int i = blockIdx.x * blockDim.x + threadIdx.x;
    if (i >= nE) return;
    int shift = *flagp;
    int s, d;
    load_edge(ei, shift, nE, i, s, d);
    unsafeAtomicAdd(&out2[d], hd[s]);
}

__global__ void finf_kernel(const float* __restrict__ out2, const float* __restrict__ hd,
                            const float* __restrict__ dinv, const float* __restrict__ b2,
                            float* __restrict__ out, int nN) {
    int d = blockIdx.x * blockDim.x + threadIdx.x;
    if (d >= nN) return;
    float z = fmaf(dinv[d], out2[d] + hd[d], b2[0]);
    out[d] = 1.f / (1.f + expf(-z));
}

extern "C" void kernel_launch(void* const* d_in, const int* in_sizes, int n_in,
                              void* d_out, int out_size, void* d_ws, size_t ws_size,
                              hipStream_t stream) {
    const float* x  = (const float*)d_in[0];
    const int*   ei = (const int*)d_in[1];
    const float* W1 = (const float*)d_in[2];
    const float* b1 = (const float*)d_in[3];
    const float* W2 = (const float*)d_in[4];
    const float* b2 = (const float*)d_in[5];
    float* out = (float*)d_out;

    const int nE = NE, nN = NN;
    const int bs = 256;
    char* ws = (char*)d_ws;
    const size_t MiB = 1 << 20;

    // bucket-path layout: hist@0 (0.96MiB)  bsum@1MiB  flag@1MiB+64K
    //                     dinv@2MiB  xd@6MiB  hd@14MiB  pairs@18MiB (128MB)
    const size_t csr_need = 18 * MiB + (size_t)nE * 4;

    if (ws_size >= csr_need) {
        int*          hist  = (int*)ws;
        int*          bsum  = (int*)(ws + 1 * MiB);
        int*          flag  = (int*)(ws + 1 * MiB + 65536);
        float*        dinv  = (float*)(ws + 2 * MiB);
        float2*       xd    = (float2*)(ws + 6 * MiB);
        float*        hd    = (float*)(ws + 14 * MiB);
        unsigned int* pairs = (unsigned int*)(ws + 18 * MiB);

        detect_kernel<<<1, 256, 0, stream>>>(ei, flag);
        passA_kernel<<<GAB, 1024, 0, stream>>>(ei, hist, flag, nE);
        scan1_kernel<<<NBS, SCAN_B, 0, stream>>>(hist, bsum, NL);
        scan2_kernel<<<1, 1024, 0, stream>>>(bsum, NBS);
        passC_kernel<<<GAB, 1024, 0, stream>>>(ei, hist, bsum, pairs, flag, nE);
        passD0_kernel<<<NB, 1024, 0, stream>>>(pairs, hist, bsum, (const float2*)x,
                                               dinv, xd, nE, nN);
        passL1_kernel<<<NB, 1024, 0, stream>>>(pairs, hist, bsum, dinv, xd,
                                               W1, b1, W2, hd, nE, nN);
        passL2_kernel<<<NB, 1024, 0, stream>>>(pairs, hist, bsum, dinv, hd,
                                               b2, out, nE, nN);
    } else {
        // fallback layout: deg@0  agg@4..12  out2@12  dinv@16  xd@20..28  hd@28  flag@32MiB
        int*    deg  = (int*)ws;
        float*  agg  = (float*)(ws + 4 * MiB);
        float*  out2 = (float*)(ws + 12 * MiB);
        float*  dinv = (float*)(ws + 16 * MiB);
        float2* xd   = (float2*)(ws + 20 * MiB);
        float*  hd   = (float*)(ws + 28 * MiB);
        int*    flag = (int*)(ws + 32 * MiB);

        hipMemsetAsync(ws, 0, 16 * MiB, stream);

        detect_kernel<<<1, 256, 0, stream>>>(ei, flag);
        deg_kernel<<<(nE + bs - 1) / bs, bs, 0, stream>>>(ei, deg, flag, nE);
        prep_kernel<<<(nN + bs - 1) / bs, bs, 0, stream>>>(deg, (const float2*)x, dinv, xd, nN);
        l1a_kernel<<<(nE + bs - 1) / bs, bs, 0, stream>>>(ei, xd, agg, flag, nE);
        h2f_kernel<<<(nN + bs - 1) / bs, bs, 0, stream>>>((const float2*)agg, xd, dinv,
                                                          W1, b1, W2, hd, nN);
        l2a_kernel<<<(nE + bs - 1) / bs, bs, 0, stream>>>(ei, hd, out2, flag, nE);
        finf_kernel<<<(nN + bs - 1) / bs, bs, 0, stream>>>(out2, hd, dinv, b2, out, nN);
    }
}

// Round 2
// 1168.069 us; speedup vs baseline: 1.1471x; 1.1471x over previous
//
#include <hip/hip_runtime.h>

#define NN 1000000
#define NE 32000000
#define SCAN_B 256

// bucket decomposition: bucket = d >> 12, 4096 nodes per bucket
#define BK_SH 12
#define BK_SZ 4096
#define NB 245                       // ceil(NN / BK_SZ)
#define GAB 512                      // edge-chunk blocks for passes A and C
#define CHUNK 62500                  // 512 * 62500 = 32,000,000 exactly (div by 4)
#define NL (NB * GAB)                // hist length = 125440 (divisible by 256)
#define NBS (NL / SCAN_B)            // 490 scan blocks (exact)

// phase-filtered aggregation: edges are NOT physically grouped by src; instead
// L1 sweeps the (L3-resident, 128MB) pairs list 4x, each sweep touching only
// src in a 2MB slice of xd -> slice is L2-resident per XCD. L2 pass uses 2
// sweeps over hd (2MB slices).
#define L1_PH 4
#define L1_SH 18                     // src quartile = s >> 18
#define L2_PH 2
#define L2_SH 19                     // src half = s >> 19

typedef int vi4 __attribute__((ext_vector_type(4)));

// ---- dtype detector: flag=1 if edge_index is int64, 0 if int32 ----
// int64 little-endian values < 2^31 have all-zero high (odd) words.
__global__ void detect_kernel(const int* __restrict__ ei, int* __restrict__ flag) {
    __shared__ int nz;
    if (threadIdx.x == 0) nz = 0;
    __syncthreads();
    int w = ei[2 * threadIdx.x + 1];
    if (w != 0) atomicAdd(&nz, 1);
    __syncthreads();
    if (threadIdx.x == 0) *flag = (nz == 0) ? 1 : 0;
}

// ---- pass A: per-block LDS histogram over buckets -> hist[b*GAB + g] ----
__global__ void passA_kernel(const int* __restrict__ ei, int* __restrict__ hist,
                             const int* __restrict__ flagp, int nE) {
    __shared__ int h[NB];
    int t = threadIdx.x;
    for (int b = t; b < NB; b += 512) h[b] = 0;
    __syncthreads();
    int shift = *flagp;
    int start = blockIdx.x * CHUNK;
    int end = min(start + CHUNK, nE);
    if (shift == 0) {
        const int* dstp = ei + nE;
        for (int i = start + (t << 2); i < end; i += 2048) {
            vi4 d = __builtin_nontemporal_load((const vi4*)(dstp + i));
            atomicAdd(&h[d.x >> BK_SH], 1);
            atomicAdd(&h[d.y >> BK_SH], 1);
            atomicAdd(&h[d.z >> BK_SH], 1);
            atomicAdd(&h[d.w >> BK_SH], 1);
        }
    } else {
        const int* dstp = ei + ((size_t)nE << 1);
        for (int i = start + t; i < end; i += 512) {
            int d = __builtin_nontemporal_load(dstp + ((size_t)i << 1));
            atomicAdd(&h[d >> BK_SH], 1);
        }
    }
    __syncthreads();
    for (int b = t; b < NB; b += 512)
        hist[(size_t)b * GAB + blockIdx.x] = h[b];
}

// ---- scan stage 1: per-block exclusive scan (in-place), block sums ----
__global__ void scan1_kernel(int* __restrict__ data, int* __restrict__ bsum, int n) {
    __shared__ int sm[SCAN_B];
    int t = threadIdx.x;
    int i = blockIdx.x * SCAN_B + t;
    int v = (i < n) ? data[i] : 0;
    sm[t] = v;
    __syncthreads();
    for (int o = 1; o < SCAN_B; o <<= 1) {
        int a = (t >= o) ? sm[t - o] : 0;
        __syncthreads();
        sm[t] += a;
        __syncthreads();
    }
    if (i < n) data[i] = sm[t] - v;
    if (t == SCAN_B - 1) bsum[blockIdx.x] = sm[t];
}

// ---- scan stage 2: exclusive scan of block sums (1 block, up to 4096) ----
__global__ void scan2_kernel(int* __restrict__ bsum, int nb) {
    __shared__ int sm[1024];
    int t = threadIdx.x;
    int base = t * 4;
    int v[4];
    int s = 0;
#pragma unroll
    for (int j = 0; j < 4; ++j) {
        v[j] = (base + j < nb) ? bsum[base + j] : 0;
        s += v[j];
    }
    sm[t] = s;
    __syncthreads();
    for (int o = 1; o < 1024; o <<= 1) {
        int a = (t >= o) ? sm[t - o] : 0;
        __syncthreads();
        sm[t] += a;
        __syncthreads();
    }
    int run = sm[t] - s;
#pragma unroll
    for (int j = 0; j < 4; ++j) {
        if (base + j < nb) bsum[base + j] = run;
        run += v[j];
    }
}

// ---- pass C: scatter packed edges into bucket-contiguous regions ----
// pairs[idx] = s | (d_local << 20)   (s < 2^20, d_local < 2^12)
__global__ void passC_kernel(const int* __restrict__ ei, const int* __restrict__ hist,
                             const int* __restrict__ bsum, unsigned int* __restrict__ pairs,
                             const int* __restrict__ flagp, int nE) {
    __shared__ int cur[NB];
    int t = threadIdx.x;
    for (int b = t; b < NB; b += 512) {
        int flat = b * GAB + blockIdx.x;
        cur[b] = hist[flat] + bsum[flat >> 8];
    }
    __syncthreads();
    int shift = *flagp;
    int start = blockIdx.x * CHUNK;
    int end = min(start + CHUNK, nE);
    if (shift == 0) {
        const int* srcp = ei;
        const int* dstp = ei + nE;
        for (int i = start + (t << 2); i < end; i += 2048) {
            vi4 s = __builtin_nontemporal_load((const vi4*)(srcp + i));
            vi4 d = __builtin_nontemporal_load((const vi4*)(dstp + i));
            int idx;
            idx = atomicAdd(&cur[d.x >> BK_SH], 1);
            pairs[idx] = (unsigned)s.x | ((unsigned)(d.x & (BK_SZ - 1)) << 20);
            idx = atomicAdd(&cur[d.y >> BK_SH], 1);
            pairs[idx] = (unsigned)s.y | ((unsigned)(d.y & (BK_SZ - 1)) << 20);
            idx = atomicAdd(&cur[d.z >> BK_SH], 1);
            pairs[idx] = (unsigned)s.z | ((unsigned)(d.z & (BK_SZ - 1)) << 20);
            idx = atomicAdd(&cur[d.w >> BK_SH], 1);
            pairs[idx] = (unsigned)s.w | ((unsigned)(d.w & (BK_SZ - 1)) << 20);
        }
    } else {
        for (int i = start + t; i < end; i += 512) {
            int s = __builtin_nontemporal_load(ei + ((size_t)i << 1));
            int d = __builtin_nontemporal_load(ei + ((size_t)nE << 1) + ((size_t)i << 1));
            int idx = atomicAdd(&cur[d >> BK_SH], 1);
            pairs[idx] = (unsigned)s | ((unsigned)(d & (BK_SZ - 1)) << 20);
        }
    }
}

__device__ __forceinline__ void bucket_range(const int* __restrict__ hist,
                                             const int* __restrict__ bsum,
                                             int b, int nE, int& base, int& endp) {
    int f0 = b * GAB;
    base = hist[f0] + bsum[f0 >> 8];
    if (b + 1 < NB) {
        int f1 = (b + 1) * GAB;
        endp = hist[f1] + bsum[f1 >> 8];
    } else {
        endp = nE;
    }
}

// ---- pass D0: per-bucket degree count -> dinv, xd = x * dinv ----
// plain loads (NOT nontemporal): keep pairs hot in L3 for the L1/L2 sweeps.
__global__ void passD0_kernel(const unsigned int* __restrict__ pairs,
                              const int* __restrict__ hist, const int* __restrict__ bsum,
                              const float2* __restrict__ x,
                              float* __restrict__ dinv, float2* __restrict__ xd,
                              int nE, int nN) {
    __shared__ int degl[BK_SZ];
    int t = threadIdx.x;
    int b = blockIdx.x;
    for (int j = t; j < BK_SZ; j += 1024) degl[j] = 0;
    __syncthreads();
    int base, endp;
    bucket_range(hist, bsum, b, nE, base, endp);
    for (int k = base + (t << 2); k < endp; k += 4096) {
#pragma unroll
        for (int j = 0; j < 4; ++j)
            if (k + j < endp) {
                unsigned int p = pairs[k + j];
                atomicAdd(&degl[p >> 20], 1);
            }
    }
    __syncthreads();
    for (int j = t; j < BK_SZ; j += 1024) {
        int nid = (b << BK_SH) + j;
        if (nid < nN) {
            float di = rsqrtf((float)(degl[j] + 1));   // +1 self-loop
            dinv[nid] = di;
            float2 v = x[nid];
            xd[nid] = make_float2(v.x * di, v.y * di);
        }
    }
}

// ---- pass L1: phase-filtered aggregate xd, fuse W1/b1/relu/W2 -> hd = h2*dinv ----
__global__ void passL1_kernel(const unsigned int* __restrict__ pairs,
                              const int* __restrict__ hist, const int* __restrict__ bsum,
                              const float* __restrict__ dinv, const float2* __restrict__ xd,
                              const float* __restrict__ W1, const float* __restrict__ b1,
                              const float* __restrict__ W2,
                              float* __restrict__ hd, int nE, int nN) {
    __shared__ float ax[BK_SZ];
    __shared__ float ay[BK_SZ];
    int t = threadIdx.x;
    int b = blockIdx.x;
    for (int j = t; j < BK_SZ; j += 1024) { ax[j] = 0.f; ay[j] = 0.f; }
    __syncthreads();
    int base, endp;
    bucket_range(hist, bsum, b, nE, base, endp);
    // 4 sweeps over the bucket's (L3-resident) edge list; sweep ph gathers only
    // src in [ph*256K, (ph+1)*256K) -> 2MB xd slice, L2-resident per XCD.
    for (int ph = 0; ph < L1_PH; ++ph) {
        for (int k = base + (t << 2); k < endp; k += 4096) {
            unsigned int p[4];
            int lim = min(4, endp - k);
#pragma unroll
            for (int j = 0; j < 4; ++j)
                if (j < lim) p[j] = pairs[k + j];
#pragma unroll
            for (int j = 0; j < 4; ++j)
                if (j < lim) {
                    unsigned int s = p[j] & 0xFFFFFu;
                    if ((int)(s >> L1_SH) == ph) {
                        float2 v = xd[s];
                        int dl = p[j] >> 20;
                        atomicAdd(&ax[dl], v.x);
                        atomicAdd(&ay[dl], v.y);
                    }
                }
        }
        __syncthreads();   // keep block's waves phase-aligned
    }
    for (int j = t; j < BK_SZ; j += 1024) {
        int nid = (b << BK_SH) + j;
        if (nid < nN) {
            float dd = dinv[nid];
            float2 xs = xd[nid];
            float AX = (ax[j] + xs.x * dd) * dd;       // self-loop: xd*dd
            float AY = (ay[j] + xs.y * dd) * dd;
            float acc = 0.f;
#pragma unroll
            for (int c = 0; c < 8; ++c) {
                float h = fmaf(AX, W1[c], fmaf(AY, W1[8 + c], b1[c]));
                acc = fmaf(fmaxf(h, 0.f), W2[c], acc);
            }
            hd[nid] = acc * dd;                        // hd = h2 * dinv
        }
    }
}

// ---- pass L2: phase-filtered aggregate hd, fuse sigmoid -> out ----
__global__ void passL2_kernel(const unsigned int* __restrict__ pairs,
                              const int* __restrict__ hist, const int* __restrict__ bsum,
                              const float* __restrict__ dinv, const float* __restrict__ hd,
                              const float* __restrict__ b2,
                              float* __restrict__ out, int nE, int nN) {
    __shared__ float ag[BK_SZ];
    int t = threadIdx.x;
    int b = blockIdx.x;
    for (int j = t; j < BK_SZ; j += 1024) ag[j] = 0.f;
    __syncthreads();
    int base, endp;
    bucket_range(hist, bsum, b, nE, base, endp);
    // 2 sweeps; sweep ph gathers only src in a 2MB hd slice.
    for (int ph = 0; ph < L2_PH; ++ph) {
        for (int k = base + (t << 2); k < endp; k += 4096) {
            unsigned int p[4];
            int lim = min(4, endp - k);
#pragma unroll
            for (int j = 0; j < 4; ++j)
                if (j < lim) p[j] = pairs[k + j];
#pragma unroll
            for (int j = 0; j < 4; ++j)
                if (j < lim) {
                    unsigned int s = p[j] & 0xFFFFFu;
                    if ((int)(s >> L2_SH) == ph)
                        atomicAdd(&ag[p[j] >> 20], hd[s]);
                }
        }
        __syncthreads();
    }
    for (int j = t; j < BK_SZ; j += 1024) {
        int nid = (b << BK_SH) + j;
        if (nid < nN) {
            float z = fmaf(dinv[nid], ag[j] + hd[nid], b2[0]);
            out[nid] = 1.f / (1.f + expf(-z));
        }
    }
}

// ================= fallback (small-workspace) atomic path =================

__global__ void deg_kernel(const int* __restrict__ ei, int* __restrict__ deg,
                           const int* __restrict__ flagp, int nE) {
    int i = blockIdx.x * blockDim.x + threadIdx.x;
    if (i >= nE) return;
    int shift = *flagp;
    int d = ei[((size_t)nE << shift) + ((size_t)i << shift)];
    atomicAdd(&deg[d], 1);
}

__global__ void prep_kernel(const int* __restrict__ deg, const float2* __restrict__ x,
                            float* __restrict__ dinv, float2* __restrict__ xd, int nN) {
    int i = blockIdx.x * blockDim.x + threadIdx.x;
    if (i >= nN) return;
    float di = rsqrtf((float)(deg[i] + 1));
    dinv[i] = di;
    float2 v = x[i];
    xd[i] = make_float2(v.x * di, v.y * di);
}

__device__ __forceinline__ void load_edge(const int* __restrict__ ei, int shift,
                                          int nE, int i, int& s, int& d) {
    s = ei[(size_t)i << shift];
    d = ei[((size_t)nE << shift) + ((size_t)i << shift)];
}

__global__ void l1a_kernel(const int* __restrict__ ei, const float2* __restrict__ xd,
                           float* __restrict__ agg, const int* __restrict__ flagp, int nE) {
    int i = blockIdx.x * blockDim.x + threadIdx.x;
    if (i >= nE) return;
    int shift = *flagp;
    int s, d;
    load_edge(ei, shift, nE, i, s, d);
    float2 v = xd[s];
    unsafeAtomicAdd(&agg[(size_t)d * 2], v.x);
    unsafeAtomicAdd(&agg[(size_t)d * 2 + 1], v.y);
}

__global__ void h2f_kernel(const float2* __restrict__ agg, const float2* __restrict__ xd,
                           const float* __restrict__ dinv, const float* __restrict__ W1,
                           const float* __restrict__ b1, const float* __restrict__ W2,
                           float* __restrict__ hd, int nN) {
    int d = blockIdx.x * blockDim.x + threadIdx.x;
    if (d >= nN) return;
    float dd = dinv[d];
    float2 a = agg[d];
    float2 xs = xd[d];
    float ax = (a.x + xs.x * dd) * dd;
    float ay = (a.y + xs.y * dd) * dd;
    float acc = 0.f;
#pragma unroll
    for (int j = 0; j < 8; ++j) {
        float h = fmaf(ax, W1[j], fmaf(ay, W1[8 + j], b1[j]));
        acc = fmaf(fmaxf(h, 0.f), W2[j], acc);
    }
    hd[d] = acc * dd;
}

__global__ void l2a_kernel(const int* __restrict__ ei, const float* __restrict__ hd,
                           float* __restrict__ out2, const int* __restrict__ flagp, int nE) {
    int i = blockIdx.x * blockDim.x + threadIdx.x;
    if (i >= nE) return;
    int shift = *flagp;
    int s, d;
    load_edge(ei, shift, nE, i, s, d);
    unsafeAtomicAdd(&out2[d], hd[s]);
}

__global__ void finf_kernel(const float* __restrict__ out2, const float* __restrict__ hd,
                            const float* __restrict__ dinv, const float* __restrict__ b2,
                            float* __restrict__ out, int nN) {
    int d = blockIdx.x * blockDim.x + threadIdx.x;
    if (d >= nN) return;
    float z = fmaf(dinv[d], out2[d] + hd[d], b2[0]);
    out[d] = 1.f / (1.f + expf(-z));
}

extern "C" void kernel_launch(void* const* d_in, const int* in_sizes, int n_in,
                              void* d_out, int out_size, void* d_ws, size_t ws_size,
                              hipStream_t stream) {
    const float* x  = (const float*)d_in[0];
    const int*   ei = (const int*)d_in[1];
    const float* W1 = (const float*)d_in[2];
    const float* b1 = (const float*)d_in[3];
    const float* W2 = (const float*)d_in[4];
    const float* b2 = (const float*)d_in[5];
    float* out = (float*)d_out;

    const int nE = NE, nN = NN;
    const int bs = 256;
    char* ws = (char*)d_ws;
    const size_t MiB = 1 << 20;

    // bucket-path layout: hist@0 (0.48MiB)  bsum@1MiB  flag@1MiB+64K
    //                     dinv@2MiB  xd@6MiB  hd@14MiB  pairs@18MiB (128MB)
    const size_t csr_need = 18 * MiB + (size_t)nE * 4;

    if (ws_size >= csr_need) {
        int*          hist  = (int*)ws;
        int*          bsum  = (int*)(ws + 1 * MiB);
        int*          flag  = (int*)(ws + 1 * MiB + 65536);
        float*        dinv  = (float*)(ws + 2 * MiB);
        float2*       xd    = (float2*)(ws + 6 * MiB);
        float*        hd    = (float*)(ws + 14 * MiB);
        unsigned int* pairs = (unsigned int*)(ws + 18 * MiB);

        detect_kernel<<<1, 256, 0, stream>>>(ei, flag);
        passA_kernel<<<GAB, 512, 0, stream>>>(ei, hist, flag, nE);
        scan1_kernel<<<NBS, SCAN_B, 0, stream>>>(hist, bsum, NL);
        scan2_kernel<<<1, 1024, 0, stream>>>(bsum, NBS);
        passC_kernel<<<GAB, 512, 0, stream>>>(ei, hist, bsum, pairs, flag, nE);
        passD0_kernel<<<NB, 1024, 0, stream>>>(pairs, hist, bsum, (const float2*)x,
                                               dinv, xd, nE, nN);
        passL1_kernel<<<NB, 1024, 0, stream>>>(pairs, hist, bsum, dinv, xd,
                                               W1, b1, W2, hd, nE, nN);
        passL2_kernel<<<NB, 1024, 0, stream>>>(pairs, hist, bsum, dinv, hd,
                                               b2, out, nE, nN);
    } else {
        // fallback layout: deg@0  agg@4..12  out2@12  dinv@16  xd@20..28  hd@28  flag@32MiB
        int*    deg  = (int*)ws;
        float*  agg  = (float*)(ws + 4 * MiB);
        float*  out2 = (float*)(ws + 12 * MiB);
        float*  dinv = (float*)(ws + 16 * MiB);
        float2* xd   = (float2*)(ws + 20 * MiB);
        float*  hd   = (float*)(ws + 28 * MiB);
        int*    flag = (int*)(ws + 32 * MiB);

        hipMemsetAsync(ws, 0, 16 * MiB, stream);

        detect_kernel<<<1, 256, 0, stream>>>(ei, flag);
        deg_kernel<<<(nE + bs - 1) / bs, bs, 0, stream>>>(ei, deg, flag, nE);
        prep_kernel<<<(nN + bs - 1) / bs, bs, 0, stream>>>(deg, (const float2*)x, dinv, xd, nN);
        l1a_kernel<<<(nE + bs - 1) / bs, bs, 0, stream>>>(ei, xd, agg, flag, nE);
        h2f_kernel<<<(nN + bs - 1) / bs, bs, 0, stream>>>((const float2*)agg, xd, dinv,
                                                          W1, b1, W2, hd, nN);
        l2a_kernel<<<(nE + bs - 1) / bs, bs, 0, stream>>>(ei, hd, out2, flag, nE);
        finf_kernel<<<(nN + bs - 1) / bs, bs, 0, stream>>>(out2, hd, dinv, b2, out, nN);
    }
}